// Round 1
// baseline (693.105 us; speedup 1.0000x reference)
//
#include <hip/hip_runtime.h>
#include <stdint.h>

#define NROW 4096
#define NDIM 128
#define KNEG 4092
#define INF_VAL 1e30f

// ---------------- Threefry-2x32-20, key = (0, 42) ----------------
__device__ __forceinline__ uint32_t rotl32(uint32_t v, int d) {
  return (v << d) | (v >> (32 - d));
}

__device__ __forceinline__ void threefry2x32(uint32_t x0, uint32_t x1,
                                             uint32_t& y0, uint32_t& y1) {
  const uint32_t k0 = 0u, k1 = 42u;
  const uint32_t k2 = 0x1BD11BDAu ^ k0 ^ k1;
  uint32_t v0 = x0 + k0, v1 = x1 + k1;
#define TF_R(r) v0 += v1; v1 = rotl32(v1, r); v1 ^= v0;
  TF_R(13) TF_R(15) TF_R(26) TF_R(6)
  v0 += k1; v1 += k2 + 1u;
  TF_R(17) TF_R(29) TF_R(16) TF_R(24)
  v0 += k2; v1 += k0 + 2u;
  TF_R(13) TF_R(15) TF_R(26) TF_R(6)
  v0 += k0; v1 += k1 + 3u;
  TF_R(17) TF_R(29) TF_R(16) TF_R(24)
  v0 += k1; v1 += k2 + 4u;
  TF_R(13) TF_R(15) TF_R(26) TF_R(6)
  v0 += k2; v1 += k0 + 5u;
#undef TF_R
  y0 = v0; y1 = v1;
}

// GUMBEL_VARIANT: 0 = partitionable, 32-bit bits = low word (y1)  [primary guess]
//                 1 = partitionable, bits = y0
//                 2 = partitionable, bits = y0 ^ y1
//                 3 = original split-iota path
#define GUMBEL_VARIANT 0

__device__ __forceinline__ float gumbel_ref(uint32_t f) {
  uint32_t y0, y1, bits;
#if GUMBEL_VARIANT == 3
  const uint32_t half = (uint32_t)NROW * (uint32_t)KNEG / 2u; // 8380416
  if (f < half) { threefry2x32(f, f + half, y0, y1); bits = y0; }
  else          { threefry2x32(f - half, f, y0, y1); bits = y1; }
#else
  threefry2x32(0u, f, y0, y1);
#if GUMBEL_VARIANT == 0
  bits = y1;
#elif GUMBEL_VARIANT == 1
  bits = y0;
#else
  bits = y0 ^ y1;
#endif
#endif
  uint32_t m = bits >> 9; // keep 23 mantissa bits
  float u;
  if (m == 0u) u = 1.17549435e-38f;              // jnp.finfo(f32).tiny clamp
  else u = __uint_as_float(m | 0x3f800000u) - 1.0f; // exact m * 2^-23
  return -logf(-logf(u));
}

__device__ __forceinline__ float softplus_ref(float x) {
  // jax.nn.softplus = logaddexp(x, 0) = max(x,0) + log1p(exp(-|x|))
  return fmaxf(x, 0.0f) + log1pf(expf(-fabsf(x)));
}

// ---------------- kernel A: row sum of squares ----------------
__global__ __launch_bounds__(64) void sumsq_kernel(const float* __restrict__ X,
                                                   float* __restrict__ sq) {
  int i = blockIdx.x;
  int lane = threadIdx.x;
  float2 v = ((const float2*)(X + (size_t)i * NDIM))[lane];
  float s = v.x * v.x + v.y * v.y;
  for (int o = 32; o > 0; o >>= 1) s += __shfl_down(s, o);
  if (lane == 0) sq[i] = s;
}

// ---------------- kernel B: distance matrix ----------------
__global__ __launch_bounds__(256) void dist_kernel(const float* __restrict__ X,
                                                   const float* __restrict__ sq,
                                                   float* __restrict__ dist) {
  __shared__ alignas(16) float A[64 * 65];
  __shared__ alignas(16) float B[64 * 65];
  const int bi = blockIdx.y, bj = blockIdx.x, tid = threadIdx.x;
  const int ty = tid >> 4, tx = tid & 15;
  float acc[4][4] = {{0.f}};

  for (int k0 = 0; k0 < NDIM; k0 += 64) {
    __syncthreads();
    for (int t = tid; t < 1024; t += 256) {
      int r = t >> 4, w = (t & 15) << 2;
      float4 a = *(const float4*)(X + ((size_t)(bi * 64 + r)) * NDIM + k0 + w);
      A[r * 65 + w + 0] = a.x; A[r * 65 + w + 1] = a.y;
      A[r * 65 + w + 2] = a.z; A[r * 65 + w + 3] = a.w;
      float4 b = *(const float4*)(X + ((size_t)(bj * 64 + r)) * NDIM + k0 + w);
      B[r * 65 + w + 0] = b.x; B[r * 65 + w + 1] = b.y;
      B[r * 65 + w + 2] = b.z; B[r * 65 + w + 3] = b.w;
    }
    __syncthreads();
#pragma unroll 8
    for (int k = 0; k < 64; ++k) {
      float av[4], bv[4];
#pragma unroll
      for (int r = 0; r < 4; ++r) av[r] = A[(ty * 4 + r) * 65 + k];
#pragma unroll
      for (int c = 0; c < 4; ++c) bv[c] = B[(tx * 4 + c) * 65 + k];
#pragma unroll
      for (int r = 0; r < 4; ++r)
#pragma unroll
        for (int c = 0; c < 4; ++c) acc[r][c] = fmaf(av[r], bv[c], acc[r][c]);
    }
  }

  const int i0 = bi * 64 + ty * 4, j0 = bj * 64 + tx * 4;
  float sqj0 = sq[j0 + 0], sqj1 = sq[j0 + 1], sqj2 = sq[j0 + 2], sqj3 = sq[j0 + 3];
#pragma unroll
  for (int r = 0; r < 4; ++r) {
    int i = i0 + r;
    float sqi = sq[i];
    float4 o;
    o.x = sqrtf(fmaxf(sqi + sqj0 - 2.0f * acc[r][0], 1e-12f));
    o.y = sqrtf(fmaxf(sqi + sqj1 - 2.0f * acc[r][1], 1e-12f));
    o.z = sqrtf(fmaxf(sqi + sqj2 - 2.0f * acc[r][2], 1e-12f));
    o.w = sqrtf(fmaxf(sqi + sqj3 - 2.0f * acc[r][3], 1e-12f));
    *(float4*)(dist + (size_t)i * NROW + j0) = o;
  }
}

// ---------------- kernel C: per-row sort + sample + loss ----------------
__global__ __launch_bounds__(256) void row_kernel(const float* __restrict__ dist,
                                                  double* __restrict__ acc) {
  __shared__ alignas(16) float v[NROW];
  __shared__ alignas(16) float sc[NROW];
  __shared__ float red[256];
  __shared__ int redi[256];
  __shared__ float s_pos[3];
  __shared__ int s_sel[3];

  const int i = blockIdx.x;
  const int tid = threadIdx.x;
  const float* row = dist + (size_t)i * NROW;

  // load row (float4)
  for (int t = tid; t < NROW / 4; t += 256)
    ((float4*)v)[t] = ((const float4*)row)[t];
  __syncthreads();

  // extract positives, mask same-class block (incl. self) to INF
  if (tid == 0) {
    int base = (i >> 2) << 2;
    float p[3]; int np = 0;
    for (int q = 0; q < 4; ++q) {
      int j = base + q;
      if (j != i) p[np++] = v[j];
      v[j] = INF_VAL;
    }
    float a = p[0], b = p[1], c = p[2], t_;
    if (a > b) { t_ = a; a = b; b = t_; }
    if (b > c) { t_ = b; b = c; c = t_; }
    if (a > b) { t_ = a; a = b; b = t_; }
    s_pos[0] = a; s_pos[1] = b; s_pos[2] = c;
  }
  __syncthreads();

  // bitonic sort ascending, 4096 elements, 256 threads (8 pairs/thread/pass)
  for (int k = 2; k <= NROW; k <<= 1) {
    for (int j = k >> 1; j > 0; j >>= 1) {
      for (int t = tid; t < NROW / 2; t += 256) {
        int idx = ((t & ~(j - 1)) << 1) | (t & (j - 1));
        int l = idx | j;
        bool asc = (idx & k) == 0;
        float a = v[idx], b = v[l];
        if (asc ? (a > b) : (a < b)) { v[idx] = b; v[l] = a; }
      }
      __syncthreads();
    }
  }

  // mean over negatives (first 4092)
  float ls = 0.0f;
  for (int j = tid; j < KNEG; j += 256) ls += v[j];
  red[tid] = ls; __syncthreads();
  for (int s = 128; s > 0; s >>= 1) { if (tid < s) red[tid] += red[tid + s]; __syncthreads(); }
  const float negsum = red[0];
  const float mean = negsum / (float)KNEG;
  __syncthreads();

  // variance (two-pass, matching mean((v-mean)^2))
  float ls2 = 0.0f;
  for (int j = tid; j < KNEG; j += 256) { float z = v[j] - mean; ls2 += z * z; }
  red[tid] = ls2; __syncthreads();
  for (int s = 128; s > 0; s >>= 1) { if (tid < s) red[tid] += red[tid + s]; __syncthreads(); }
  const float var = red[0] / (float)KNEG;
  const float stdv = sqrtf(var);
  const float denom = 2.0f * (stdv * stdv);
  __syncthreads();

  // scores = log_prob + gumbel
  const uint32_t fbase = (uint32_t)i * (uint32_t)KNEG;
  for (int j = tid; j < NROW; j += 256) {
    if (j < KNEG) {
      float z = v[j] - mean;
      sc[j] = (z * z) / denom + gumbel_ref(fbase + (uint32_t)j);
    } else {
      sc[j] = -1e38f;
    }
  }
  __syncthreads();

  // top-3 by score (ties -> smaller index), selection order = descending score
  for (int t = 0; t < 3; ++t) {
    float bs = -1e38f; int bj = 0x7fffffff;
    for (int j = tid; j < NROW; j += 256) {
      float s = sc[j];
      if (s > bs) { bs = s; bj = j; }
    }
    red[tid] = bs; redi[tid] = bj; __syncthreads();
    for (int s = 128; s > 0; s >>= 1) {
      if (tid < s) {
        float so = red[tid + s]; int jo = redi[tid + s];
        if (so > red[tid] || (so == red[tid] && jo < redi[tid])) {
          red[tid] = so; redi[tid] = jo;
        }
      }
      __syncthreads();
    }
    if (tid == 0) { s_sel[t] = redi[0]; sc[redi[0]] = -1e38f; }
    __syncthreads();
  }

  // epilogue
  if (tid == 0) {
    float p0 = s_pos[0], p1 = s_pos[1], p2 = s_pos[2];
    float thr = p2 + 0.05f;
    float samp[3]; bool kept[3]; int cnt = 0;
#pragma unroll
    for (int t = 0; t < 3; ++t) {
      samp[t] = v[s_sel[t]];
      kept[t] = samp[t] < thr;
      cnt += kept[t] ? 1 : 0;
    }
    bool any = cnt > 0;
    float pos_loss = 0.5f *
        (softplus_ref(-2.0f * (1.0f - p0)) + softplus_ref(-2.0f * (1.0f - p1)) +
         softplus_ref(-2.0f * (1.0f - p2))) / 3.0f;
    float nsum = 0.0f;
#pragma unroll
    for (int t = 0; t < 3; ++t)
      if (kept[t]) nsum += softplus_ref(20.0f * (1.0f - samp[t]));
    float neg_loss = 0.05f * nsum / (float)(cnt > 0 ? cnt : 1);
    float row_loss = any ? (pos_loss + neg_loss) : 0.0f;
    int first = kept[0] ? 0 : (kept[1] ? 1 : (kept[2] ? 2 : 0));
    float neg0 = samp[first];
    float errv = (any && (p0 < neg0 - 0.1f)) ? 1.0f : 0.0f;
    atomicAdd(acc + 0, (double)row_loss);
    atomicAdd(acc + 1, (double)errv);
    atomicAdd(acc + 2, (double)(p0 + p1 + p2));
    atomicAdd(acc + 3, (double)negsum);
  }
}

// ---------------- finalize ----------------
__global__ void finalize_kernel(const double* __restrict__ acc,
                                float* __restrict__ out) {
  out[0] = (float)(acc[0] / (double)NROW);
  out[1] = (float)(1.0 - acc[1] / (double)NROW);
  out[2] = (float)(acc[2] / ((double)NROW * 3.0));
  out[3] = (float)(acc[3] / ((double)NROW * (double)KNEG));
}

extern "C" void kernel_launch(void* const* d_in, const int* in_sizes, int n_in,
                              void* d_out, int out_size, void* d_ws, size_t ws_size,
                              hipStream_t stream) {
  (void)in_sizes; (void)n_in; (void)out_size; (void)ws_size;
  const float* X = (const float*)d_in[0];
  float* out = (float*)d_out;
  char* ws = (char*)d_ws;

  float* dist = (float*)ws;                                     // 64 MiB
  float* sq = (float*)(ws + (size_t)NROW * NROW * sizeof(float));
  double* acc = (double*)(ws + (size_t)NROW * NROW * sizeof(float) +
                          (size_t)NROW * sizeof(float));

  hipMemsetAsync(acc, 0, 4 * sizeof(double), stream);
  sumsq_kernel<<<NROW, 64, 0, stream>>>(X, sq);
  dim3 gb(NROW / 64, NROW / 64);
  dist_kernel<<<gb, 256, 0, stream>>>(X, sq, dist);
  row_kernel<<<NROW, 256, 0, stream>>>(dist, acc);
  finalize_kernel<<<1, 1, 0, stream>>>(acc, out);
}

// Round 2
// 443.383 us; speedup vs baseline: 1.5632x; 1.5632x over previous
//
#include <hip/hip_runtime.h>
#include <stdint.h>

#define NROW 4096
#define NDIM 128
#define KNEG 4092
#define INF_VAL 1e30f
#define BUCKETS 4096
#define BSCALE 128.0f
#define BLIMIT 31.99f

// ---------------- Threefry-2x32-20, key = (0, 42) ----------------
__device__ __forceinline__ uint32_t rotl32(uint32_t v, int d) {
  return (v << d) | (v >> (32 - d));
}

__device__ __forceinline__ void threefry2x32(uint32_t x0, uint32_t x1,
                                             uint32_t& y0, uint32_t& y1) {
  const uint32_t k0 = 0u, k1 = 42u;
  const uint32_t k2 = 0x1BD11BDAu ^ k0 ^ k1;
  uint32_t v0 = x0 + k0, v1 = x1 + k1;
#define TF_R(r) v0 += v1; v1 = rotl32(v1, r); v1 ^= v0;
  TF_R(13) TF_R(15) TF_R(26) TF_R(6)
  v0 += k1; v1 += k2 + 1u;
  TF_R(17) TF_R(29) TF_R(16) TF_R(24)
  v0 += k2; v1 += k0 + 2u;
  TF_R(13) TF_R(15) TF_R(26) TF_R(6)
  v0 += k0; v1 += k1 + 3u;
  TF_R(17) TF_R(29) TF_R(16) TF_R(24)
  v0 += k1; v1 += k2 + 4u;
  TF_R(13) TF_R(15) TF_R(26) TF_R(6)
  v0 += k2; v1 += k0 + 5u;
#undef TF_R
  y0 = v0; y1 = v1;
}

// partitionable threefry, 32-bit bits = low word (y1) — verified correct in R1
__device__ __forceinline__ float gumbel_ref(uint32_t f) {
  uint32_t y0, y1;
  threefry2x32(0u, f, y0, y1);
  uint32_t m = y1 >> 9; // 23 mantissa bits
  float u;
  if (m == 0u) u = 1.17549435e-38f;                 // tiny clamp
  else u = __uint_as_float(m | 0x3f800000u) - 1.0f; // exact m * 2^-23
  return -logf(-logf(u));
}

__device__ __forceinline__ float softplus_ref(float x) {
  return fmaxf(x, 0.0f) + log1pf(expf(-fabsf(x)));
}

__device__ __forceinline__ int bucket_of(float x) {
  // monotone; exact ordering restored by within-bucket float compares
  return (x < BLIMIT) ? (int)(x * BSCALE) : (BUCKETS - 1);
}

// ---------------- kernel A: row sum of squares ----------------
__global__ __launch_bounds__(64) void sumsq_kernel(const float* __restrict__ X,
                                                   float* __restrict__ sq) {
  int i = blockIdx.x;
  int lane = threadIdx.x;
  float2 v = ((const float2*)(X + (size_t)i * NDIM))[lane];
  float s = v.x * v.x + v.y * v.y;
  for (int o = 32; o > 0; o >>= 1) s += __shfl_down(s, o);
  if (lane == 0) sq[i] = s;
}

// ---------------- kernel B: distance matrix ----------------
__global__ __launch_bounds__(256) void dist_kernel(const float* __restrict__ X,
                                                   const float* __restrict__ sq,
                                                   float* __restrict__ dist) {
  __shared__ alignas(16) float A[64 * 65];
  __shared__ alignas(16) float B[64 * 65];
  const int bi = blockIdx.y, bj = blockIdx.x, tid = threadIdx.x;
  const int ty = tid >> 4, tx = tid & 15;
  float acc[4][4] = {{0.f}};

  for (int k0 = 0; k0 < NDIM; k0 += 64) {
    __syncthreads();
    for (int t = tid; t < 1024; t += 256) {
      int r = t >> 4, w = (t & 15) << 2;
      float4 a = *(const float4*)(X + ((size_t)(bi * 64 + r)) * NDIM + k0 + w);
      A[r * 65 + w + 0] = a.x; A[r * 65 + w + 1] = a.y;
      A[r * 65 + w + 2] = a.z; A[r * 65 + w + 3] = a.w;
      float4 b = *(const float4*)(X + ((size_t)(bj * 64 + r)) * NDIM + k0 + w);
      B[r * 65 + w + 0] = b.x; B[r * 65 + w + 1] = b.y;
      B[r * 65 + w + 2] = b.z; B[r * 65 + w + 3] = b.w;
    }
    __syncthreads();
#pragma unroll 8
    for (int k = 0; k < 64; ++k) {
      float av[4], bv[4];
#pragma unroll
      for (int r = 0; r < 4; ++r) av[r] = A[(ty * 4 + r) * 65 + k];
#pragma unroll
      for (int c = 0; c < 4; ++c) bv[c] = B[(tx * 4 + c) * 65 + k];
#pragma unroll
      for (int r = 0; r < 4; ++r)
#pragma unroll
        for (int c = 0; c < 4; ++c) acc[r][c] = fmaf(av[r], bv[c], acc[r][c]);
    }
  }

  const int i0 = bi * 64 + ty * 4, j0 = bj * 64 + tx * 4;
  float sqj0 = sq[j0 + 0], sqj1 = sq[j0 + 1], sqj2 = sq[j0 + 2], sqj3 = sq[j0 + 3];
#pragma unroll
  for (int r = 0; r < 4; ++r) {
    int i = i0 + r;
    float sqi = sq[i];
    float4 o;
    o.x = sqrtf(fmaxf(sqi + sqj0 - 2.0f * acc[r][0], 1e-12f));
    o.y = sqrtf(fmaxf(sqi + sqj1 - 2.0f * acc[r][1], 1e-12f));
    o.z = sqrtf(fmaxf(sqi + sqj2 - 2.0f * acc[r][2], 1e-12f));
    o.w = sqrtf(fmaxf(sqi + sqj3 - 2.0f * acc[r][3], 1e-12f));
    *(float4*)(dist + (size_t)i * NROW + j0) = o;
  }
}

// ---------------- kernel C: per-row bucket-rank + sample + loss ----------------
// Replaces the full bitonic sort. score(rank j) = z(v_(j))^2/(2s^2) + gumbel(j)
// needs only each element's RANK; mean/std are permutation-invariant.
__global__ __launch_bounds__(256) void row_kernel(const float* __restrict__ dist,
                                                  double* __restrict__ acc) {
  __shared__ int   base[BUCKETS];   // hist -> excl prefix -> bucket END after scatter
  __shared__ float sorted[NROW];    // bucket-grouped values (unsorted within bucket)
  __shared__ float cscore[768];
  __shared__ int   crank[768];
  __shared__ float cx[768];
  __shared__ float redf[256];
  __shared__ int   redi[256];
  __shared__ int   redi2[256];
  __shared__ float s_pos[3];
  __shared__ float s_sel[3];

  const int i = blockIdx.x;
  const int tid = threadIdx.x;
  const float* row = dist + (size_t)i * NROW;
  const int gbase = i & ~3;

  // ---- load 16 values into registers, mask same-class block to INF ----
  float x[16];
  {
    const float4* r4 = (const float4*)row;
#pragma unroll
    for (int q4 = 0; q4 < 4; ++q4) {
      float4 f = r4[tid * 4 + q4];
      x[q4 * 4 + 0] = f.x; x[q4 * 4 + 1] = f.y;
      x[q4 * 4 + 2] = f.z; x[q4 * 4 + 3] = f.w;
    }
  }
#pragma unroll
  for (int q = 0; q < 16; ++q) {
    int j = tid * 16 + q;
    if ((j >> 2) == (i >> 2)) x[q] = INF_VAL;
  }

  // ---- positives (3 smallest = all 3, sorted) ----
  if (tid == 0) {
    float p[3]; int np = 0;
    for (int q = 0; q < 4; ++q) {
      int j = gbase + q;
      if (j != i) p[np++] = row[j];
    }
    float a = p[0], b = p[1], c = p[2], t_;
    if (a > b) { t_ = a; a = b; b = t_; }
    if (b > c) { t_ = b; b = c; c = t_; }
    if (a > b) { t_ = a; a = b; b = t_; }
    s_pos[0] = a; s_pos[1] = b; s_pos[2] = c;
  }

  // ---- mean over negatives (permutation-invariant) ----
  float ls = 0.f;
#pragma unroll
  for (int q = 0; q < 16; ++q) if (x[q] < 1e29f) ls += x[q];
  redf[tid] = ls; __syncthreads();
  for (int s = 128; s > 0; s >>= 1) { if (tid < s) redf[tid] += redf[tid + s]; __syncthreads(); }
  const float negsum = redf[0];
  const float mean = negsum / (float)KNEG;
  __syncthreads();

  // ---- variance (two-pass, matches ref) ----
  float ls2 = 0.f;
#pragma unroll
  for (int q = 0; q < 16; ++q) if (x[q] < 1e29f) { float z = x[q] - mean; ls2 += z * z; }
  redf[tid] = ls2; __syncthreads();
  for (int s = 128; s > 0; s >>= 1) { if (tid < s) redf[tid] += redf[tid + s]; __syncthreads(); }
  const float var = redf[0] / (float)KNEG;
  const float stdv = sqrtf(var);
  const float denom = 2.0f * (stdv * stdv);
  __syncthreads();

  // ---- histogram ----
  for (int k = tid; k < BUCKETS; k += 256) base[k] = 0;
  __syncthreads();
#pragma unroll
  for (int q = 0; q < 16; ++q) atomicAdd(&base[bucket_of(x[q])], 1);
  __syncthreads();

  // ---- exclusive scan over 4096 buckets ----
  int c16[16]; int lsum = 0;
#pragma unroll
  for (int q = 0; q < 16; ++q) { int t_ = base[tid * 16 + q]; c16[q] = lsum; lsum += t_; }
  redi[tid] = lsum; __syncthreads();
  int val = lsum;
  for (int off = 1; off < 256; off <<= 1) {
    int other = (tid >= off) ? redi[tid - off] : 0;
    __syncthreads();
    if (tid >= off) { val += other; redi[tid] = val; }
    __syncthreads();
  }
  int eblk = val - lsum;
#pragma unroll
  for (int q = 0; q < 16; ++q) base[tid * 16 + q] = eblk + c16[q];
  __syncthreads();

  // ---- scatter into bucket-grouped array (base[b] becomes bucket END) ----
#pragma unroll
  for (int q = 0; q < 16; ++q) {
    int b = bucket_of(x[q]);
    int p = atomicAdd(&base[b], 1);
    sorted[p] = x[q];
  }
  __syncthreads();

  // ---- per-element exact rank, score, per-thread top-3 ----
  const uint32_t fbase = (uint32_t)i * (uint32_t)KNEG;
  float t0s = -1e38f, t1s = -1e38f, t2s = -1e38f;
  int   t0r = 0x7fffffff, t1r = 0x7fffffff, t2r = 0x7fffffff;
  float t0x = 0.f, t1x = 0.f, t2x = 0.f;
  for (int q = 0; q < 16; ++q) {
    int p = tid * 16 + q;
    float xv = sorted[p];
    int b = bucket_of(xv);
    int s0 = (b == 0) ? 0 : base[b - 1]; // end of b-1 == start of b
    int e0 = base[b];
    int cnt = 0;
    for (int u = s0; u < e0; ++u) {
      float o = sorted[u];
      if (o < xv || (o == xv && u < p)) ++cnt;
    }
    int rank = s0 + cnt;
    if (rank < KNEG) {
      float z = xv - mean;
      float sv = z * z / denom + gumbel_ref(fbase + (uint32_t)rank);
      if (sv > t2s || (sv == t2s && rank < t2r)) {
        t2s = sv; t2r = rank; t2x = xv;
        if (t2s > t1s || (t2s == t1s && t2r < t1r)) {
          float ts = t1s; int tr = t1r; float tx = t1x;
          t1s = t2s; t1r = t2r; t1x = t2x; t2s = ts; t2r = tr; t2x = tx;
        }
        if (t1s > t0s || (t1s == t0s && t1r < t0r)) {
          float ts = t0s; int tr = t0r; float tx = t0x;
          t0s = t1s; t0r = t1r; t0x = t1x; t1s = ts; t1r = tr; t1x = tx;
        }
      }
    }
  }
  cscore[tid * 3 + 0] = t0s; crank[tid * 3 + 0] = t0r; cx[tid * 3 + 0] = t0x;
  cscore[tid * 3 + 1] = t1s; crank[tid * 3 + 1] = t1r; cx[tid * 3 + 1] = t1x;
  cscore[tid * 3 + 2] = t2s; crank[tid * 3 + 2] = t2r; cx[tid * 3 + 2] = t2x;
  __syncthreads();

  // ---- block top-3 over 768 candidates (score desc, rank asc) ----
  for (int t = 0; t < 3; ++t) {
    float bs = -1e38f; int br = 0x7fffffff; int bi = 0;
    for (int k = tid; k < 768; k += 256) {
      float s_ = cscore[k]; int r_ = crank[k];
      if (s_ > bs || (s_ == bs && r_ < br)) { bs = s_; br = r_; bi = k; }
    }
    redf[tid] = bs; redi[tid] = br; redi2[tid] = bi; __syncthreads();
    for (int s = 128; s > 0; s >>= 1) {
      if (tid < s) {
        float so = redf[tid + s]; int ro = redi[tid + s];
        if (so > redf[tid] || (so == redf[tid] && ro < redi[tid])) {
          redf[tid] = so; redi[tid] = ro; redi2[tid] = redi2[tid + s];
        }
      }
      __syncthreads();
    }
    if (tid == 0) { int w = redi2[0]; s_sel[t] = cx[w]; cscore[w] = -1e38f; }
    __syncthreads();
  }

  // ---- epilogue ----
  if (tid == 0) {
    float p0 = s_pos[0], p1 = s_pos[1], p2 = s_pos[2];
    float thr = p2 + 0.05f;
    float samp[3]; bool kept[3]; int cnt = 0;
#pragma unroll
    for (int t = 0; t < 3; ++t) {
      samp[t] = s_sel[t];
      kept[t] = samp[t] < thr;
      cnt += kept[t] ? 1 : 0;
    }
    bool any = cnt > 0;
    float pos_loss = 0.5f *
        (softplus_ref(-2.0f * (1.0f - p0)) + softplus_ref(-2.0f * (1.0f - p1)) +
         softplus_ref(-2.0f * (1.0f - p2))) / 3.0f;
    float nsum = 0.0f;
#pragma unroll
    for (int t = 0; t < 3; ++t)
      if (kept[t]) nsum += softplus_ref(20.0f * (1.0f - samp[t]));
    float neg_loss = 0.05f * nsum / (float)(cnt > 0 ? cnt : 1);
    float row_loss = any ? (pos_loss + neg_loss) : 0.0f;
    int first = kept[0] ? 0 : (kept[1] ? 1 : (kept[2] ? 2 : 0));
    float neg0 = samp[first];
    float errv = (any && (p0 < neg0 - 0.1f)) ? 1.0f : 0.0f;
    atomicAdd(acc + 0, (double)row_loss);
    atomicAdd(acc + 1, (double)errv);
    atomicAdd(acc + 2, (double)(p0 + p1 + p2));
    atomicAdd(acc + 3, (double)negsum);
  }
}

// ---------------- finalize ----------------
__global__ void finalize_kernel(const double* __restrict__ acc,
                                float* __restrict__ out) {
  out[0] = (float)(acc[0] / (double)NROW);
  out[1] = (float)(1.0 - acc[1] / (double)NROW);
  out[2] = (float)(acc[2] / ((double)NROW * 3.0));
  out[3] = (float)(acc[3] / ((double)NROW * (double)KNEG));
}

extern "C" void kernel_launch(void* const* d_in, const int* in_sizes, int n_in,
                              void* d_out, int out_size, void* d_ws, size_t ws_size,
                              hipStream_t stream) {
  (void)in_sizes; (void)n_in; (void)out_size; (void)ws_size;
  const float* X = (const float*)d_in[0];
  float* out = (float*)d_out;
  char* ws = (char*)d_ws;

  float* dist = (float*)ws;                                     // 64 MiB
  float* sq = (float*)(ws + (size_t)NROW * NROW * sizeof(float));
  double* acc = (double*)(ws + (size_t)NROW * NROW * sizeof(float) +
                          (size_t)NROW * sizeof(float));

  hipMemsetAsync(acc, 0, 4 * sizeof(double), stream);
  sumsq_kernel<<<NROW, 64, 0, stream>>>(X, sq);
  dim3 gb(NROW / 64, NROW / 64);
  dist_kernel<<<gb, 256, 0, stream>>>(X, sq, dist);
  row_kernel<<<NROW, 256, 0, stream>>>(dist, acc);
  finalize_kernel<<<1, 1, 0, stream>>>(acc, out);
}

// Round 3
// 401.717 us; speedup vs baseline: 1.7254x; 1.1037x over previous
//
#include <hip/hip_runtime.h>
#include <stdint.h>

#define NROW 4096
#define NDIM 128
#define KNEG 4092
#define INF_VAL 1e30f
#define BUCKETS 4096
#define BSCALE 128.0f
#define BLIMIT 31.99f

// ---------------- Threefry-2x32-20, key = (0, 42) ----------------
__device__ __forceinline__ uint32_t rotl32(uint32_t v, int d) {
  return (v << d) | (v >> (32 - d));
}

__device__ __forceinline__ void threefry2x32(uint32_t x0, uint32_t x1,
                                             uint32_t& y0, uint32_t& y1) {
  const uint32_t k0 = 0u, k1 = 42u;
  const uint32_t k2 = 0x1BD11BDAu ^ k0 ^ k1;
  uint32_t v0 = x0 + k0, v1 = x1 + k1;
#define TF_R(r) v0 += v1; v1 = rotl32(v1, r); v1 ^= v0;
  TF_R(13) TF_R(15) TF_R(26) TF_R(6)
  v0 += k1; v1 += k2 + 1u;
  TF_R(17) TF_R(29) TF_R(16) TF_R(24)
  v0 += k2; v1 += k0 + 2u;
  TF_R(13) TF_R(15) TF_R(26) TF_R(6)
  v0 += k0; v1 += k1 + 3u;
  TF_R(17) TF_R(29) TF_R(16) TF_R(24)
  v0 += k1; v1 += k2 + 4u;
  TF_R(13) TF_R(15) TF_R(26) TF_R(6)
  v0 += k2; v1 += k0 + 5u;
#undef TF_R
  y0 = v0; y1 = v1;
}

// partitionable threefry, bits = y1 — verified correct in R1 (absmax = bf16 ulp)
__device__ __forceinline__ float gumbel_ref(uint32_t f) {
  uint32_t y0, y1;
  threefry2x32(0u, f, y0, y1);
  uint32_t m = y1 >> 9;
  float u;
  if (m == 0u) u = 1.17549435e-38f;
  else u = __uint_as_float(m | 0x3f800000u) - 1.0f;
  float nl = -__logf(u);
  return -__logf(nl);
}

__device__ __forceinline__ float softplus_ref(float x) {
  return fmaxf(x, 0.0f) + log1pf(expf(-fabsf(x)));
}

__device__ __forceinline__ int bucket_of(float x) {
  return (x < BLIMIT) ? (int)(x * BSCALE) : (BUCKETS - 1);
}

// ---------------- kernel A: row sum of squares ----------------
__global__ __launch_bounds__(64) void sumsq_kernel(const float* __restrict__ X,
                                                   float* __restrict__ sq) {
  int i = blockIdx.x;
  int lane = threadIdx.x;
  float2 v = ((const float2*)(X + (size_t)i * NDIM))[lane];
  float s = v.x * v.x + v.y * v.y;
  for (int o = 32; o > 0; o >>= 1) s += __shfl_down(s, o);
  if (lane == 0) sq[i] = s;
}

// ---------------- kernel B: distance matrix (128x128 tile, 8x8/thread) ----------------
#define TBM 128
#define TBK 32
__global__ __launch_bounds__(256, 4) void dist_kernel(const float* __restrict__ X,
                                                      const float* __restrict__ sq,
                                                      float* __restrict__ dist) {
  __shared__ alignas(16) float As[TBK][TBM + 4]; // k-major, +4 keeps b128 align
  __shared__ alignas(16) float Bs[TBK][TBM + 4];
  const int bi = blockIdx.y, bj = blockIdx.x, tid = threadIdx.x;
  const int tx = tid & 15, ty = tid >> 4;
  float acc[8][8] = {{0.f}};

  for (int k0 = 0; k0 < NDIM; k0 += TBK) {
#pragma unroll
    for (int q = 0; q < 4; ++q) {
      int s = tid + 256 * q;        // 0..1023 slots of float4
      int r = s >> 3;               // row 0..127
      int c = (s & 7) << 2;         // col 0,4,..,28
      float4 a = *(const float4*)(X + (size_t)(bi * TBM + r) * NDIM + k0 + c);
      As[c + 0][r] = a.x; As[c + 1][r] = a.y;
      As[c + 2][r] = a.z; As[c + 3][r] = a.w;
      float4 b = *(const float4*)(X + (size_t)(bj * TBM + r) * NDIM + k0 + c);
      Bs[c + 0][r] = b.x; Bs[c + 1][r] = b.y;
      Bs[c + 2][r] = b.z; Bs[c + 3][r] = b.w;
    }
    __syncthreads();
#pragma unroll
    for (int kk = 0; kk < TBK; ++kk) {
      float4 a0 = *(const float4*)&As[kk][ty * 8];
      float4 a1 = *(const float4*)&As[kk][ty * 8 + 4];
      float4 b0 = *(const float4*)&Bs[kk][tx * 8];
      float4 b1 = *(const float4*)&Bs[kk][tx * 8 + 4];
      float av[8] = {a0.x, a0.y, a0.z, a0.w, a1.x, a1.y, a1.z, a1.w};
      float bv[8] = {b0.x, b0.y, b0.z, b0.w, b1.x, b1.y, b1.z, b1.w};
#pragma unroll
      for (int r = 0; r < 8; ++r)
#pragma unroll
        for (int c = 0; c < 8; ++c) acc[r][c] = fmaf(av[r], bv[c], acc[r][c]);
    }
    __syncthreads();
  }

  const int i0 = bi * TBM + ty * 8, j0 = bj * TBM + tx * 8;
  float sqj[8];
#pragma unroll
  for (int c = 0; c < 8; ++c) sqj[c] = sq[j0 + c];
#pragma unroll
  for (int r = 0; r < 8; ++r) {
    float sqi = sq[i0 + r];
    float4 o0, o1;
    o0.x = sqrtf(fmaxf(sqi + sqj[0] - 2.0f * acc[r][0], 1e-12f));
    o0.y = sqrtf(fmaxf(sqi + sqj[1] - 2.0f * acc[r][1], 1e-12f));
    o0.z = sqrtf(fmaxf(sqi + sqj[2] - 2.0f * acc[r][2], 1e-12f));
    o0.w = sqrtf(fmaxf(sqi + sqj[3] - 2.0f * acc[r][3], 1e-12f));
    o1.x = sqrtf(fmaxf(sqi + sqj[4] - 2.0f * acc[r][4], 1e-12f));
    o1.y = sqrtf(fmaxf(sqi + sqj[5] - 2.0f * acc[r][5], 1e-12f));
    o1.z = sqrtf(fmaxf(sqi + sqj[6] - 2.0f * acc[r][6], 1e-12f));
    o1.w = sqrtf(fmaxf(sqi + sqj[7] - 2.0f * acc[r][7], 1e-12f));
    *(float4*)(dist + (size_t)(i0 + r) * NROW + j0) = o0;
    *(float4*)(dist + (size_t)(i0 + r) * NROW + j0 + 4) = o1;
  }
}

// ---------------- kernel C: per-row bucket-rank + sample + loss ----------------
__global__ __launch_bounds__(256) void row_kernel(const float* __restrict__ dist,
                                                  double* __restrict__ acc) {
  __shared__ alignas(16) float sorted[NROW];  // reduce scratch aliases after rank loop
  __shared__ alignas(16) int base[BUCKETS];   // candidate arrays alias after rank loop
  __shared__ float wredf[8];
  __shared__ int wtot[4];
  __shared__ float s_pos[3];
  __shared__ float s_sel[3];

  float* cscore = (float*)base;           // 768 (alias: valid after rank loop)
  int*   crank  = base + 768;             // 768
  float* cx     = (float*)(base + 1536);  // 768
  float* redf   = sorted;                 // 256 (alias: valid after rank loop)
  int*   redi   = (int*)sorted + 256;
  int*   redi2  = (int*)sorted + 512;

  const int i = blockIdx.x;
  const int tid = threadIdx.x;
  const int lane = tid & 63, wid = tid >> 6;
  const float* row = dist + (size_t)i * NROW;

  // ---- load 16 values into registers, mask same-class block to INF ----
  float x[16];
  {
    const float4* r4 = (const float4*)row;
#pragma unroll
    for (int q4 = 0; q4 < 4; ++q4) {
      float4 f = r4[tid * 4 + q4];
      x[q4 * 4 + 0] = f.x; x[q4 * 4 + 1] = f.y;
      x[q4 * 4 + 2] = f.z; x[q4 * 4 + 3] = f.w;
    }
  }
#pragma unroll
  for (int q = 0; q < 16; ++q) {
    int j = tid * 16 + q;
    if ((j >> 2) == (i >> 2)) x[q] = INF_VAL;
  }

  // ---- positives ----
  if (tid == 0) {
    int gbase = i & ~3;
    float p[3]; int np = 0;
    for (int q = 0; q < 4; ++q) {
      int j = gbase + q;
      if (j != i) p[np++] = row[j];
    }
    float a = p[0], b = p[1], c = p[2], t_;
    if (a > b) { t_ = a; a = b; b = t_; }
    if (b > c) { t_ = b; b = c; c = t_; }
    if (a > b) { t_ = a; a = b; b = t_; }
    s_pos[0] = a; s_pos[1] = b; s_pos[2] = c;
  }

  // ---- mean (wave shfl reduce + cross-wave) ----
  float ls = 0.f;
#pragma unroll
  for (int q = 0; q < 16; ++q) if (x[q] < 1e29f) ls += x[q];
  for (int o = 32; o > 0; o >>= 1) ls += __shfl_down(ls, o);
  if (lane == 0) wredf[wid] = ls;
  __syncthreads();
  const float negsum = wredf[0] + wredf[1] + wredf[2] + wredf[3];
  const float mean = negsum / (float)KNEG;

  // ---- variance (two-pass) ----
  float ls2 = 0.f;
#pragma unroll
  for (int q = 0; q < 16; ++q) if (x[q] < 1e29f) { float z = x[q] - mean; ls2 += z * z; }
  for (int o = 32; o > 0; o >>= 1) ls2 += __shfl_down(ls2, o);
  if (lane == 0) wredf[4 + wid] = ls2;
  __syncthreads();
  const float var = (wredf[4] + wredf[5] + wredf[6] + wredf[7]) / (float)KNEG;
  const float stdv = sqrtf(var);
  const float rdenom = __frcp_rn(2.0f * stdv * stdv);

  // ---- histogram ----
  for (int k = tid; k < BUCKETS; k += 256) base[k] = 0;
  __syncthreads();
#pragma unroll
  for (int q = 0; q < 16; ++q) atomicAdd(&base[bucket_of(x[q])], 1);
  __syncthreads();

  // ---- exclusive scan over 4096 buckets (wave shfl scan) ----
  int c16[16]; int lsum = 0;
#pragma unroll
  for (int q = 0; q < 16; ++q) { int t_ = base[tid * 16 + q]; c16[q] = lsum; lsum += t_; }
  int incl = lsum;
  for (int off = 1; off < 64; off <<= 1) {
    int o = __shfl_up(incl, off);
    if (lane >= off) incl += o;
  }
  if (lane == 63) wtot[wid] = incl;
  __syncthreads();
  int excl = incl - lsum;
#pragma unroll
  for (int w = 0; w < 4; ++w) if (w < wid) excl += wtot[w];
#pragma unroll
  for (int q = 0; q < 16; ++q) base[tid * 16 + q] = excl + c16[q];
  __syncthreads();

  // ---- scatter (base[b] becomes bucket END) ----
#pragma unroll
  for (int q = 0; q < 16; ++q) {
    int b = bucket_of(x[q]);
    int p = atomicAdd(&base[b], 1);
    sorted[p] = x[q];
  }
  __syncthreads();

  // ---- per-element exact rank + score + per-thread top-3 ----
  // positions p = tid + 256*q: coalesced loads, near-broadcast bucket scans
  const uint32_t fbase = (uint32_t)i * (uint32_t)KNEG;
  float t0s = -1e38f, t1s = -1e38f, t2s = -1e38f;
  int   t0r = 0x7fffffff, t1r = 0x7fffffff, t2r = 0x7fffffff;
  float t0x = 0.f, t1x = 0.f, t2x = 0.f;
  for (int q = 0; q < 16; ++q) {
    int p = tid + 256 * q;
    float xv = sorted[p];
    int b = bucket_of(xv);
    int s0 = (b == 0) ? 0 : base[b - 1];
    int e0 = base[b];
    int cnt = 0;
    for (int u = s0; u < e0; ++u) {
      float o = sorted[u];
      cnt += (o < xv || (o == xv && u < p)) ? 1 : 0;
    }
    int rank = s0 + cnt;
    if (rank < KNEG) {
      float z = xv - mean;
      float sv = z * z * rdenom + gumbel_ref(fbase + (uint32_t)rank);
      if (sv > t2s || (sv == t2s && rank < t2r)) {
        t2s = sv; t2r = rank; t2x = xv;
        if (t2s > t1s || (t2s == t1s && t2r < t1r)) {
          float ts = t1s; int tr = t1r; float tx = t1x;
          t1s = t2s; t1r = t2r; t1x = t2x; t2s = ts; t2r = tr; t2x = tx;
        }
        if (t1s > t0s || (t1s == t0s && t1r < t0r)) {
          float ts = t0s; int tr = t0r; float tx = t0x;
          t0s = t1s; t0r = t1r; t0x = t1x; t1s = ts; t1r = tr; t1x = tx;
        }
      }
    }
  }
  __syncthreads();  // base/sorted reads done; aliases become live

  cscore[tid * 3 + 0] = t0s; crank[tid * 3 + 0] = t0r; cx[tid * 3 + 0] = t0x;
  cscore[tid * 3 + 1] = t1s; crank[tid * 3 + 1] = t1r; cx[tid * 3 + 1] = t1x;
  cscore[tid * 3 + 2] = t2s; crank[tid * 3 + 2] = t2r; cx[tid * 3 + 2] = t2x;
  __syncthreads();

  // ---- block top-3 over 768 candidates (score desc, rank asc) ----
  for (int t = 0; t < 3; ++t) {
    float bs = -1e38f; int br = 0x7fffffff; int bidx = 0;
    for (int k = tid; k < 768; k += 256) {
      float s_ = cscore[k]; int r_ = crank[k];
      if (s_ > bs || (s_ == bs && r_ < br)) { bs = s_; br = r_; bidx = k; }
    }
    redf[tid] = bs; redi[tid] = br; redi2[tid] = bidx;
    __syncthreads();
    if (tid < 64) {
      float s0_ = redf[tid]; int r0_ = redi[tid]; int i0_ = redi2[tid];
#pragma unroll
      for (int o = 64; o < 256; o += 64) {
        float s1 = redf[tid + o]; int r1 = redi[tid + o];
        if (s1 > s0_ || (s1 == s0_ && r1 < r0_)) { s0_ = s1; r0_ = r1; i0_ = redi2[tid + o]; }
      }
      for (int off = 32; off > 0; off >>= 1) {
        float s1 = __shfl_down(s0_, off);
        int r1 = __shfl_down(r0_, off);
        int i1 = __shfl_down(i0_, off);
        if (s1 > s0_ || (s1 == s0_ && r1 < r0_)) { s0_ = s1; r0_ = r1; i0_ = i1; }
      }
      if (tid == 0) { s_sel[t] = cx[i0_]; cscore[i0_] = -1e38f; }
    }
    __syncthreads();
  }

  // ---- epilogue ----
  if (tid == 0) {
    float p0 = s_pos[0], p1 = s_pos[1], p2 = s_pos[2];
    float thr = p2 + 0.05f;
    float samp[3]; bool kept[3]; int cnt = 0;
#pragma unroll
    for (int t = 0; t < 3; ++t) {
      samp[t] = s_sel[t];
      kept[t] = samp[t] < thr;
      cnt += kept[t] ? 1 : 0;
    }
    bool any = cnt > 0;
    float pos_loss = 0.5f *
        (softplus_ref(-2.0f * (1.0f - p0)) + softplus_ref(-2.0f * (1.0f - p1)) +
         softplus_ref(-2.0f * (1.0f - p2))) / 3.0f;
    float nsum = 0.0f;
#pragma unroll
    for (int t = 0; t < 3; ++t)
      if (kept[t]) nsum += softplus_ref(20.0f * (1.0f - samp[t]));
    float neg_loss = 0.05f * nsum / (float)(cnt > 0 ? cnt : 1);
    float row_loss = any ? (pos_loss + neg_loss) : 0.0f;
    int first = kept[0] ? 0 : (kept[1] ? 1 : (kept[2] ? 2 : 0));
    float neg0 = samp[first];
    float errv = (any && (p0 < neg0 - 0.1f)) ? 1.0f : 0.0f;
    atomicAdd(acc + 0, (double)row_loss);
    atomicAdd(acc + 1, (double)errv);
    atomicAdd(acc + 2, (double)(p0 + p1 + p2));
    atomicAdd(acc + 3, (double)negsum);
  }
}

// ---------------- finalize ----------------
__global__ void finalize_kernel(const double* __restrict__ acc,
                                float* __restrict__ out) {
  out[0] = (float)(acc[0] / (double)NROW);
  out[1] = (float)(1.0 - acc[1] / (double)NROW);
  out[2] = (float)(acc[2] / ((double)NROW * 3.0));
  out[3] = (float)(acc[3] / ((double)NROW * (double)KNEG));
}

extern "C" void kernel_launch(void* const* d_in, const int* in_sizes, int n_in,
                              void* d_out, int out_size, void* d_ws, size_t ws_size,
                              hipStream_t stream) {
  (void)in_sizes; (void)n_in; (void)out_size; (void)ws_size;
  const float* X = (const float*)d_in[0];
  float* out = (float*)d_out;
  char* ws = (char*)d_ws;

  float* dist = (float*)ws;                                     // 64 MiB
  float* sq = (float*)(ws + (size_t)NROW * NROW * sizeof(float));
  double* acc = (double*)(ws + (size_t)NROW * NROW * sizeof(float) +
                          (size_t)NROW * sizeof(float));

  hipMemsetAsync(acc, 0, 4 * sizeof(double), stream);
  sumsq_kernel<<<NROW, 64, 0, stream>>>(X, sq);
  dim3 gb(NROW / TBM, NROW / TBM);
  dist_kernel<<<gb, 256, 0, stream>>>(X, sq, dist);
  row_kernel<<<NROW, 256, 0, stream>>>(dist, acc);
  finalize_kernel<<<1, 1, 0, stream>>>(acc, out);
}

// Round 4
// 332.110 us; speedup vs baseline: 2.0870x; 1.2096x over previous
//
#include <hip/hip_runtime.h>
#include <stdint.h>

#define NROW 4096
#define NDIM 128
#define KNEG 4092
#define INF_VAL 1e30f
#define BUCKETS 2048

typedef __attribute__((ext_vector_type(8))) short short8;
typedef __attribute__((ext_vector_type(4))) float f32x4;

// ---------------- Threefry-2x32-20, key = (0, 42) ----------------
__device__ __forceinline__ uint32_t rotl32(uint32_t v, int d) {
  return (v << d) | (v >> (32 - d));
}

__device__ __forceinline__ void threefry2x32(uint32_t x0, uint32_t x1,
                                             uint32_t& y0, uint32_t& y1) {
  const uint32_t k0 = 0u, k1 = 42u;
  const uint32_t k2 = 0x1BD11BDAu ^ k0 ^ k1;
  uint32_t v0 = x0 + k0, v1 = x1 + k1;
#define TF_R(r) v0 += v1; v1 = rotl32(v1, r); v1 ^= v0;
  TF_R(13) TF_R(15) TF_R(26) TF_R(6)
  v0 += k1; v1 += k2 + 1u;
  TF_R(17) TF_R(29) TF_R(16) TF_R(24)
  v0 += k2; v1 += k0 + 2u;
  TF_R(13) TF_R(15) TF_R(26) TF_R(6)
  v0 += k0; v1 += k1 + 3u;
  TF_R(17) TF_R(29) TF_R(16) TF_R(24)
  v0 += k1; v1 += k2 + 4u;
  TF_R(13) TF_R(15) TF_R(26) TF_R(6)
  v0 += k2; v1 += k0 + 5u;
#undef TF_R
  y0 = v0; y1 = v1;
}

// partitionable threefry, bits = y1 — verified R1; __logf verified R3
__device__ __forceinline__ float gumbel_ref(uint32_t f) {
  uint32_t y0, y1;
  threefry2x32(0u, f, y0, y1);
  uint32_t m = y1 >> 9;
  float u;
  if (m == 0u) u = 1.17549435e-38f;
  else u = __uint_as_float(m | 0x3f800000u) - 1.0f;
  return -__logf(-__logf(u));
}

__device__ __forceinline__ float softplus_ref(float x) {
  return fmaxf(x, 0.0f) + log1pf(expf(-fabsf(x)));
}

// monotone CDF bucketization: any monotone map is rank-correct; erf equalizes
// occupancy for ~normal distances (lambda ~= 2 per bucket)
__device__ __forceinline__ int bucket_cdf(float x, float mean, float rsig) {
  float z = (x - mean) * rsig;   // rsig includes 1/sqrt(2)
  float u = erff(z);
  int b = (int)((u + 1.0f) * ((float)BUCKETS * 0.5f - 0.25f));
  return min(max(b, 0), BUCKETS - 1);
}

// ---------------- kernel A: sumsq + fp32->bf16 convert ----------------
__global__ __launch_bounds__(64) void prep_kernel(const float* __restrict__ X,
                                                  float* __restrict__ sq,
                                                  ushort* __restrict__ Xbf) {
  int i = blockIdx.x;
  int lane = threadIdx.x;
  float2 v = ((const float2*)(X + (size_t)i * NDIM))[lane];
  float s = v.x * v.x + v.y * v.y;
  for (int o = 32; o > 0; o >>= 1) s += __shfl_down(s, o);
  if (lane == 0) sq[i] = s;
  // RNE bf16 convert
  uint32_t ux = __float_as_uint(v.x);
  uint32_t uy = __float_as_uint(v.y);
  ux += 0x7fffu + ((ux >> 16) & 1u);
  uy += 0x7fffu + ((uy >> 16) & 1u);
  ushort2 h;
  h.x = (ushort)(ux >> 16);
  h.y = (ushort)(uy >> 16);
  ((ushort2*)(Xbf + (size_t)i * NDIM))[lane] = h;
}

// ---------------- kernel B: distance matrix via bf16 MFMA ----------------
// C = Xbf * Xbf^T (fp32 acc), dist = sqrt(max(sq_i+sq_j-2C, 1e-12))
// 128x128 tile, K=128 staged in two 64-halves. LDS row stride 68 bf16
// (pad +4): dword stride 34 -> lane banks 2m%32, 2-way = free.
#define DSTR 68
__global__ __launch_bounds__(256) void dist_mfma(const ushort* __restrict__ Xbf,
                                                 const float* __restrict__ sq,
                                                 float* __restrict__ dist) {
  __shared__ ushort Als[128 * DSTR];
  __shared__ ushort Bls[128 * DSTR];
  const int tid = threadIdx.x;
  const int wave = tid >> 6, lane = tid & 63;
  const int q = lane >> 4, ln = lane & 15;
  const int bi = blockIdx.y, bj = blockIdx.x;
  const ushort* Ag = Xbf + (size_t)bi * 128 * NDIM;
  const ushort* Bg = Xbf + (size_t)bj * 128 * NDIM;

  f32x4 acc[8][2];
#pragma unroll
  for (int mt = 0; mt < 8; ++mt)
#pragma unroll
    for (int nt = 0; nt < 2; ++nt) acc[mt][nt] = (f32x4){0.f, 0.f, 0.f, 0.f};

  for (int kh = 0; kh < 2; ++kh) {
    if (kh) __syncthreads();  // protect LDS reuse
#pragma unroll
    for (int t = 0; t < 4; ++t) {
      int c = tid + 256 * t;         // 1024 chunks of 8 bf16
      int r = c >> 3, k8 = (c & 7) << 3;
      *(short8*)&Als[r * DSTR + k8] =
          *(const short8*)(Ag + (size_t)r * NDIM + kh * 64 + k8);
      *(short8*)&Bls[r * DSTR + k8] =
          *(const short8*)(Bg + (size_t)r * NDIM + kh * 64 + k8);
    }
    __syncthreads();
#pragma unroll
    for (int k0 = 0; k0 < 64; k0 += 32) {
      int kf = k0 + q * 8;
      short8 a[8], b[2];
#pragma unroll
      for (int mt = 0; mt < 8; ++mt)
        a[mt] = *(const short8*)&Als[(mt * 16 + ln) * DSTR + kf];
#pragma unroll
      for (int nt = 0; nt < 2; ++nt)
        b[nt] = *(const short8*)&Bls[(wave * 32 + nt * 16 + ln) * DSTR + kf];
#pragma unroll
      for (int mt = 0; mt < 8; ++mt)
#pragma unroll
        for (int nt = 0; nt < 2; ++nt)
          acc[mt][nt] = __builtin_amdgcn_mfma_f32_16x16x32_bf16(
              a[mt], b[nt], acc[mt][nt], 0, 0, 0);
    }
  }

  // epilogue: C/D layout col=lane&15, row=q*4+reg (m89-verified)
  float sqj[2];
#pragma unroll
  for (int nt = 0; nt < 2; ++nt)
    sqj[nt] = sq[bj * 128 + wave * 32 + nt * 16 + ln];
#pragma unroll
  for (int mt = 0; mt < 8; ++mt) {
    int ibase = bi * 128 + mt * 16 + q * 4;
#pragma unroll
    for (int r = 0; r < 4; ++r) {
      int i = ibase + r;
      float sqi = sq[i];
#pragma unroll
      for (int nt = 0; nt < 2; ++nt) {
        int j = bj * 128 + wave * 32 + nt * 16 + ln;
        float d = sqi + sqj[nt] - 2.0f * acc[mt][nt][r];
        dist[(size_t)i * NROW + j] = sqrtf(fmaxf(d, 1e-12f));
      }
    }
  }
}

// ---------------- kernel C: per-row CDF-bucket rank + sample + loss ----------------
__global__ __launch_bounds__(256) void row_kernel(const float* __restrict__ dist,
                                                  double* __restrict__ acc) {
  __shared__ alignas(16) float sorted[NROW];   // 16 KB
  __shared__ alignas(16) int base[BUCKETS];    // 8 KB
  __shared__ float wredf[8];
  __shared__ int wtot[4];
  __shared__ float s_pos[3];
  __shared__ float s_sel[3];

  // aliases (live only after the rank pass; barrier-separated)
  float* cscore = (float*)base;                // 768
  float* cx     = (float*)base + 768;          // 768 (base has 2048 slots)
  int*   crank  = (int*)sorted;                // 768
  float* redf   = sorted + 1024;               // 256
  int*   redi   = (int*)(sorted + 1280);       // 256
  int*   redi2  = (int*)(sorted + 1536);       // 256

  const int i = blockIdx.x;
  const int tid = threadIdx.x;
  const int lane = tid & 63, wid = tid >> 6;
  const float* row = dist + (size_t)i * NROW;

  // ---- load 16 values, mask same-class block to INF ----
  float x[16];
  {
    const float4* r4 = (const float4*)row;
#pragma unroll
    for (int q4 = 0; q4 < 4; ++q4) {
      float4 f = r4[tid * 4 + q4];
      x[q4 * 4 + 0] = f.x; x[q4 * 4 + 1] = f.y;
      x[q4 * 4 + 2] = f.z; x[q4 * 4 + 3] = f.w;
    }
  }
#pragma unroll
  for (int qq = 0; qq < 16; ++qq) {
    int j = tid * 16 + qq;
    if ((j >> 2) == (i >> 2)) x[qq] = INF_VAL;
  }

  // ---- positives ----
  if (tid == 0) {
    int gbase = i & ~3;
    float p[3]; int np = 0;
    for (int qq = 0; qq < 4; ++qq) {
      int j = gbase + qq;
      if (j != i) p[np++] = row[j];
    }
    float a = p[0], b = p[1], c = p[2], t_;
    if (a > b) { t_ = a; a = b; b = t_; }
    if (b > c) { t_ = b; b = c; c = t_; }
    if (a > b) { t_ = a; a = b; b = t_; }
    s_pos[0] = a; s_pos[1] = b; s_pos[2] = c;
  }

  // ---- mean ----
  float ls = 0.f;
#pragma unroll
  for (int qq = 0; qq < 16; ++qq) if (x[qq] < 1e29f) ls += x[qq];
  for (int o = 32; o > 0; o >>= 1) ls += __shfl_down(ls, o);
  if (lane == 0) wredf[wid] = ls;
  __syncthreads();
  const float negsum = wredf[0] + wredf[1] + wredf[2] + wredf[3];
  const float mean = negsum / (float)KNEG;

  // ---- variance (two-pass, matches ref) ----
  float ls2 = 0.f;
#pragma unroll
  for (int qq = 0; qq < 16; ++qq)
    if (x[qq] < 1e29f) { float z = x[qq] - mean; ls2 += z * z; }
  for (int o = 32; o > 0; o >>= 1) ls2 += __shfl_down(ls2, o);
  if (lane == 0) wredf[4 + wid] = ls2;
  __syncthreads();
  const float var = (wredf[4] + wredf[5] + wredf[6] + wredf[7]) / (float)KNEG;
  const float stdv = sqrtf(var);
  const float rdenom = __frcp_rn(2.0f * stdv * stdv);
  const float rsig = 0.70710678f / stdv;

  // ---- histogram (CDF buckets) ----
  for (int k = tid; k < BUCKETS; k += 256) base[k] = 0;
  __syncthreads();
  int bkt[16];
#pragma unroll
  for (int qq = 0; qq < 16; ++qq) {
    bkt[qq] = bucket_cdf(x[qq], mean, rsig);
    atomicAdd(&base[bkt[qq]], 1);
  }
  __syncthreads();

  // ---- exclusive scan over 2048 buckets (8/thread + wave shfl) ----
  int c8[8]; int lsum = 0;
#pragma unroll
  for (int qq = 0; qq < 8; ++qq) {
    int t_ = base[tid * 8 + qq];
    c8[qq] = lsum; lsum += t_;
  }
  int incl = lsum;
  for (int off = 1; off < 64; off <<= 1) {
    int o = __shfl_up(incl, off);
    if (lane >= off) incl += o;
  }
  if (lane == 63) wtot[wid] = incl;
  __syncthreads();
  int excl = incl - lsum;
#pragma unroll
  for (int w = 0; w < 4; ++w) if (w < wid) excl += wtot[w];
#pragma unroll
  for (int qq = 0; qq < 8; ++qq) base[tid * 8 + qq] = excl + c8[qq];
  __syncthreads();

  // ---- scatter (base[b] becomes bucket END) ----
#pragma unroll
  for (int qq = 0; qq < 16; ++qq) {
    int p = atomicAdd(&base[bkt[qq]], 1);
    sorted[p] = x[qq];
  }
  __syncthreads();

  // ---- rank + score + per-thread top-3 (coalesced positions) ----
  const uint32_t fbase = (uint32_t)i * (uint32_t)KNEG;
  float t0s = -1e38f, t1s = -1e38f, t2s = -1e38f;
  int   t0r = 0x7fffffff, t1r = 0x7fffffff, t2r = 0x7fffffff;
  float t0x = 0.f, t1x = 0.f, t2x = 0.f;
  for (int qq = 0; qq < 16; ++qq) {
    int p = tid + 256 * qq;
    float xv = sorted[p];
    int b = bucket_cdf(xv, mean, rsig);
    int s0 = (b == 0) ? 0 : base[b - 1];
    int e0 = base[b];
    int cnt = 0;
    for (int u = s0; u < e0; ++u) {
      float o = sorted[u];
      cnt += (o < xv || (o == xv && u < p)) ? 1 : 0;
    }
    int rank = s0 + cnt;
    if (rank < KNEG) {
      float z = xv - mean;
      float sv = z * z * rdenom + gumbel_ref(fbase + (uint32_t)rank);
      if (sv > t2s || (sv == t2s && rank < t2r)) {
        t2s = sv; t2r = rank; t2x = xv;
        if (t2s > t1s || (t2s == t1s && t2r < t1r)) {
          float ts = t1s; int tr = t1r; float tx = t1x;
          t1s = t2s; t1r = t2r; t1x = t2x; t2s = ts; t2r = tr; t2x = tx;
        }
        if (t1s > t0s || (t1s == t0s && t1r < t0r)) {
          float ts = t0s; int tr = t0r; float tx = t0x;
          t0s = t1s; t0r = t1r; t0x = t1x; t1s = ts; t1r = tr; t1x = tx;
        }
      }
    }
  }
  __syncthreads();  // sorted/base reads done; aliases become live

  cscore[tid * 3 + 0] = t0s; crank[tid * 3 + 0] = t0r; cx[tid * 3 + 0] = t0x;
  cscore[tid * 3 + 1] = t1s; crank[tid * 3 + 1] = t1r; cx[tid * 3 + 1] = t1x;
  cscore[tid * 3 + 2] = t2s; crank[tid * 3 + 2] = t2r; cx[tid * 3 + 2] = t2x;
  __syncthreads();

  // ---- block top-3 over 768 candidates (score desc, rank asc) ----
  for (int t = 0; t < 3; ++t) {
    float bs = -1e38f; int br = 0x7fffffff; int bidx = 0;
    for (int k = tid; k < 768; k += 256) {
      float s_ = cscore[k]; int r_ = crank[k];
      if (s_ > bs || (s_ == bs && r_ < br)) { bs = s_; br = r_; bidx = k; }
    }
    redf[tid] = bs; redi[tid] = br; redi2[tid] = bidx;
    __syncthreads();
    if (tid < 64) {
      float s0_ = redf[tid]; int r0_ = redi[tid]; int i0_ = redi2[tid];
#pragma unroll
      for (int o = 64; o < 256; o += 64) {
        float s1 = redf[tid + o]; int r1 = redi[tid + o];
        if (s1 > s0_ || (s1 == s0_ && r1 < r0_)) {
          s0_ = s1; r0_ = r1; i0_ = redi2[tid + o];
        }
      }
      for (int off = 32; off > 0; off >>= 1) {
        float s1 = __shfl_down(s0_, off);
        int r1 = __shfl_down(r0_, off);
        int i1 = __shfl_down(i0_, off);
        if (s1 > s0_ || (s1 == s0_ && r1 < r0_)) { s0_ = s1; r0_ = r1; i0_ = i1; }
      }
      if (tid == 0) { s_sel[t] = cx[i0_]; cscore[i0_] = -1e38f; }
    }
    __syncthreads();
  }

  // ---- epilogue ----
  if (tid == 0) {
    float p0 = s_pos[0], p1 = s_pos[1], p2 = s_pos[2];
    float thr = p2 + 0.05f;
    float samp[3]; bool kept[3]; int cnt = 0;
#pragma unroll
    for (int t = 0; t < 3; ++t) {
      samp[t] = s_sel[t];
      kept[t] = samp[t] < thr;
      cnt += kept[t] ? 1 : 0;
    }
    bool any = cnt > 0;
    float pos_loss = 0.5f *
        (softplus_ref(-2.0f * (1.0f - p0)) + softplus_ref(-2.0f * (1.0f - p1)) +
         softplus_ref(-2.0f * (1.0f - p2))) / 3.0f;
    float nsum = 0.0f;
#pragma unroll
    for (int t = 0; t < 3; ++t)
      if (kept[t]) nsum += softplus_ref(20.0f * (1.0f - samp[t]));
    float neg_loss = 0.05f * nsum / (float)(cnt > 0 ? cnt : 1);
    float row_loss = any ? (pos_loss + neg_loss) : 0.0f;
    int first = kept[0] ? 0 : (kept[1] ? 1 : (kept[2] ? 2 : 0));
    float neg0 = samp[first];
    float errv = (any && (p0 < neg0 - 0.1f)) ? 1.0f : 0.0f;
    atomicAdd(acc + 0, (double)row_loss);
    atomicAdd(acc + 1, (double)errv);
    atomicAdd(acc + 2, (double)(p0 + p1 + p2));
    atomicAdd(acc + 3, (double)negsum);
  }
}

// ---------------- finalize ----------------
__global__ void finalize_kernel(const double* __restrict__ acc,
                                float* __restrict__ out) {
  out[0] = (float)(acc[0] / (double)NROW);
  out[1] = (float)(1.0 - acc[1] / (double)NROW);
  out[2] = (float)(acc[2] / ((double)NROW * 3.0));
  out[3] = (float)(acc[3] / ((double)NROW * (double)KNEG));
}

extern "C" void kernel_launch(void* const* d_in, const int* in_sizes, int n_in,
                              void* d_out, int out_size, void* d_ws, size_t ws_size,
                              hipStream_t stream) {
  (void)in_sizes; (void)n_in; (void)out_size; (void)ws_size;
  const float* X = (const float*)d_in[0];
  float* out = (float*)d_out;
  char* ws = (char*)d_ws;

  float* dist = (float*)ws;                                        // 64 MiB
  size_t off = (size_t)NROW * NROW * sizeof(float);
  float* sq = (float*)(ws + off);            off += NROW * sizeof(float);
  ushort* Xbf = (ushort*)(ws + off);         off += (size_t)NROW * NDIM * sizeof(ushort);
  double* acc = (double*)(ws + off);

  hipMemsetAsync(acc, 0, 4 * sizeof(double), stream);
  prep_kernel<<<NROW, 64, 0, stream>>>(X, sq, Xbf);
  dim3 gb(NROW / 128, NROW / 128);
  dist_mfma<<<gb, 256, 0, stream>>>(Xbf, sq, dist);
  row_kernel<<<NROW, 256, 0, stream>>>(dist, acc);
  finalize_kernel<<<1, 1, 0, stream>>>(acc, out);
}